// Round 2
// baseline (228.574 us; speedup 1.0000x reference)
//
#include <hip/hip_runtime.h>

#define C_DIM 28
#define HALF 14
#define HW 65536   // 256*256
#define THREADS 256
#define GRID 2048  // 2048*256 threads * 2 consecutive px = 16*65536 pixels exactly

namespace {

constexpr double K_PI = 3.14159265358979323846;

constexpr double cos_taylor(double u) {
    double u2 = u * u;
    double term = 1.0, sum = 1.0;
    for (int i = 1; i <= 12; ++i) {
        term *= -u2 / (double)((2 * i - 1) * (2 * i));
        sum += term;
    }
    return sum;
}

// cos(pi * t / 56), exact integer range reduction (period 112).
constexpr double cos_pi_over56(int t) {
    t %= 112;
    if (t < 0) t += 112;
    double sign = 1.0;
    if (t > 56) t = 112 - t;
    if (t > 28) { t = 56 - t; sign = -1.0; }
    return sign * cos_taylor(K_PI * (double)t / 56.0);
}

// Symmetry-folded tables.
// D[k][n]    = 2*cos(pi*(2n+1)k/56), n<14.  D[k][27-n] = (-1)^k D[k][n].
// Dinv[n][k] = cos(pi*(2n+1)k/56)*(k==0?0.5:1)/28, n<14.
//              Dinv[27-n][k] = (-1)^k Dinv[n][k].
struct Tables {
    float D[C_DIM][HALF];
    float Dinv[HALF][C_DIM];
};

constexpr Tables make_tables() {
    Tables t{};
    for (int k = 0; k < C_DIM; ++k)
        for (int n = 0; n < HALF; ++n)
            t.D[k][n] = (float)(2.0 * cos_pi_over56((2 * n + 1) * k));
    for (int n = 0; n < HALF; ++n)
        for (int k = 0; k < C_DIM; ++k)
            t.Dinv[n][k] = (float)(cos_pi_over56((2 * n + 1) * k) *
                                   ((k == 0) ? 0.5 : 1.0) / (double)C_DIM);
    return t;
}

constexpr Tables TBL = make_tables();

typedef float f2v __attribute__((ext_vector_type(2)));
typedef float f4v __attribute__((ext_vector_type(4)));

} // namespace

// Thread t handles two CONSECUTIVE pixels (b, hw0) and (b, hw0+1):
//   b = t >> 15, hw0 = (t & 32767)*2.
// => all x loads are dwordx2 (8 B/lane, 512 B/wave-instr, coalesced),
//    all stores are nontemporal dwordx2,
//    the two weight rows are 448 B contiguous -> 14 dwordx4 loads whose
//    union across the wave is a contiguous 14 KB block (L2/L3-resident).
// Math: symmetry-folded DCT (28 chains of length 14 per matvec), duplicated
// over the 2 pixel components.
__global__ __launch_bounds__(THREADS) void spedct_kernel(
    const float* __restrict__ x,
    const float* __restrict__ w,
    float* __restrict__ out) {

    const int t   = blockIdx.x * THREADS + threadIdx.x;  // 0..524287
    const int b   = t >> 15;                             // 0..15
    const int hw0 = (t & 32767) << 1;                    // 0..65534, even

    const float* xp = x   + (size_t)b * C_DIM * HW + hw0;
    float*       op = out + (size_t)b * C_DIM * HW + hw0;

    // ---- x: 28 dwordx2 loads, all issued before first use (latency hiding).
    // Nontemporal: each element read exactly once; keep L2/L3 for w.
    f2v xv[C_DIM];
#pragma unroll
    for (int n = 0; n < C_DIM; ++n)
        xv[n] = __builtin_nontemporal_load((const f2v*)(xp + (size_t)n * HW));

    // ---- fold: s[n] = x[n]+x[27-n], u[n] = x[n]-x[27-n]
    f2v s[HALF], u[HALF];
#pragma unroll
    for (int n = 0; n < HALF; ++n) {
        s[n].x = xv[n].x + xv[27 - n].x;
        s[n].y = xv[n].y + xv[27 - n].y;
        u[n].x = xv[n].x - xv[27 - n].x;
        u[n].y = xv[n].y - xv[27 - n].y;
    }

    // ---- weight rows hw0, hw0+1: 2*28 floats = 448 B contiguous = 14 dwordx4.
    // Issued here so L2 latency hides under the forward-DCT FMA block.
    // NOT nontemporal: w is reread once per batch b (16x) -> keep cached.
    const f4v* wp4 = (const f4v*)(w + (size_t)hw0 * C_DIM);
    f4v w0[7], w1[7];
#pragma unroll
    for (int q = 0; q < 7; ++q) w0[q] = wp4[q];      // row hw0
#pragma unroll
    for (int q = 0; q < 7; ++q) w1[q] = wp4[7 + q];  // row hw0+1

    // ---- forward: Xd = D*x via fold. Even k uses s, odd k uses u.
    // 28 independent chains of length 14, per pixel component.
    f2v xd[C_DIM];
#pragma unroll
    for (int k = 0; k < C_DIM; ++k) {
        const float c = TBL.D[k][0];
        xd[k].x = c * ((k & 1) ? u[0].x : s[0].x);
        xd[k].y = c * ((k & 1) ? u[0].y : s[0].y);
    }
#pragma unroll
    for (int n = 1; n < HALF; ++n) {
#pragma unroll
        for (int k = 0; k < C_DIM; ++k) {
            const float c = TBL.D[k][n];
            if (k & 1) {
                xd[k].x = fmaf(c, u[n].x, xd[k].x);
                xd[k].y = fmaf(c, u[n].y, xd[k].y);
            } else {
                xd[k].x = fmaf(c, s[n].x, xd[k].x);
                xd[k].y = fmaf(c, s[n].y, xd[k].y);
            }
        }
    }

    // ---- spectral filter: per-pixel weight row (register "transpose" is free:
    // component r of xd[4q+i] multiplies row-r chunk q component i).
#pragma unroll
    for (int q = 0; q < 7; ++q) {
#pragma unroll
        for (int i = 0; i < 4; ++i) {
            xd[4 * q + i].x *= w0[q][i];
            xd[4 * q + i].y *= w1[q][i];
        }
    }

    // ---- inverse: o = Dinv*xd via fold. e = even-k partial, f = odd-k partial;
    // o[n] = e+f, o[27-n] = e-f. 28 chains of length 14 per component.
    f2v e[HALF], f[HALF];
#pragma unroll
    for (int n = 0; n < HALF; ++n) {
        e[n].x = TBL.Dinv[n][0] * xd[0].x;
        e[n].y = TBL.Dinv[n][0] * xd[0].y;
        f[n].x = TBL.Dinv[n][1] * xd[1].x;
        f[n].y = TBL.Dinv[n][1] * xd[1].y;
    }
#pragma unroll
    for (int j = 1; j < HALF; ++j) {
#pragma unroll
        for (int n = 0; n < HALF; ++n) {
            const float ce = TBL.Dinv[n][2 * j];
            const float cf = TBL.Dinv[n][2 * j + 1];
            e[n].x = fmaf(ce, xd[2 * j].x, e[n].x);
            e[n].y = fmaf(ce, xd[2 * j].y, e[n].y);
            f[n].x = fmaf(cf, xd[2 * j + 1].x, f[n].x);
            f[n].y = fmaf(cf, xd[2 * j + 1].y, f[n].y);
        }
    }

    // ---- stores: 28 nontemporal dwordx2 (out written once, never read).
#pragma unroll
    for (int n = 0; n < HALF; ++n) {
        f2v lo, hi;
        lo.x = e[n].x + f[n].x;  lo.y = e[n].y + f[n].y;
        hi.x = e[n].x - f[n].x;  hi.y = e[n].y - f[n].y;
        __builtin_nontemporal_store(lo, (f2v*)(op + (size_t)n * HW));
        __builtin_nontemporal_store(hi, (f2v*)(op + (size_t)(27 - n) * HW));
    }
}

extern "C" void kernel_launch(void* const* d_in, const int* in_sizes, int n_in,
                              void* d_out, int out_size, void* d_ws, size_t ws_size,
                              hipStream_t stream) {
    const float* x = (const float*)d_in[0];   // [16,28,256,256]
    const float* w = (const float*)d_in[1];   // [256,256,28]
    float* out = (float*)d_out;               // [16,28,256,256]

    spedct_kernel<<<dim3(GRID), dim3(THREADS), 0, stream>>>(x, w, out);
}

// Round 3
// 223.121 us; speedup vs baseline: 1.0244x; 1.0244x over previous
//
#include <hip/hip_runtime.h>

#define C_DIM 28
#define HALF 14
#define HW 65536   // 256*256
#define THREADS 256
#define GRID 2048  // 2048*256 threads * 2 consecutive px = 16*65536 pixels exactly

namespace {

constexpr double K_PI = 3.14159265358979323846;

constexpr double cos_taylor(double u) {
    double u2 = u * u;
    double term = 1.0, sum = 1.0;
    for (int i = 1; i <= 12; ++i) {
        term *= -u2 / (double)((2 * i - 1) * (2 * i));
        sum += term;
    }
    return sum;
}

// cos(pi * t / 56), exact integer range reduction (period 112).
constexpr double cos_pi_over56(int t) {
    t %= 112;
    if (t < 0) t += 112;
    double sign = 1.0;
    if (t > 56) t = 112 - t;
    if (t > 28) { t = 56 - t; sign = -1.0; }
    return sign * cos_taylor(K_PI * (double)t / 56.0);
}

// Symmetry-folded tables.
// D[k][n]    = 2*cos(pi*(2n+1)k/56), n<14.  D[k][27-n] = (-1)^k D[k][n].
// Dinv[n][k] = cos(pi*(2n+1)k/56)*(k==0?0.5:1)/28, n<14.
//              Dinv[27-n][k] = (-1)^k Dinv[n][k].
struct Tables {
    float D[C_DIM][HALF];
    float Dinv[HALF][C_DIM];
};

constexpr Tables make_tables() {
    Tables t{};
    for (int k = 0; k < C_DIM; ++k)
        for (int n = 0; n < HALF; ++n)
            t.D[k][n] = (float)(2.0 * cos_pi_over56((2 * n + 1) * k));
    for (int n = 0; n < HALF; ++n)
        for (int k = 0; k < C_DIM; ++k)
            t.Dinv[n][k] = (float)(cos_pi_over56((2 * n + 1) * k) *
                                   ((k == 0) ? 0.5 : 1.0) / (double)C_DIM);
    return t;
}

constexpr Tables TBL = make_tables();

typedef float f2v __attribute__((ext_vector_type(2)));
typedef float f4v __attribute__((ext_vector_type(4)));

} // namespace

// Thread t handles two CONSECUTIVE pixels (b, hw0) and (b, hw0+1):
//   b = t >> 15, hw0 = (t & 32767)*2.
// Round-3 single-variable experiment vs round 2: stores are NORMAL (cached,
// write-back through L2 — the 6.7 TB/s memset path) instead of nontemporal.
// NT stores were the one component common to every ~70 µs measurement, and
// 117 MB / 72 µs = 1.6 TB/s matches an NT-drain-rate bottleneck exactly.
__global__ __launch_bounds__(THREADS) void spedct_kernel(
    const float* __restrict__ x,
    const float* __restrict__ w,
    float* __restrict__ out) {

    const int t   = blockIdx.x * THREADS + threadIdx.x;  // 0..524287
    const int b   = t >> 15;                             // 0..15
    const int hw0 = (t & 32767) << 1;                    // 0..65534, even

    const float* xp = x   + (size_t)b * C_DIM * HW + hw0;
    float*       op = out + (size_t)b * C_DIM * HW + hw0;

    // ---- x: 28 dwordx2 loads, all issued before first use (latency hiding).
    // Nontemporal: each element read exactly once; keep L2/L3 for w.
    f2v xv[C_DIM];
#pragma unroll
    for (int n = 0; n < C_DIM; ++n)
        xv[n] = __builtin_nontemporal_load((const f2v*)(xp + (size_t)n * HW));

    // ---- fold: s[n] = x[n]+x[27-n], u[n] = x[n]-x[27-n]
    f2v s[HALF], u[HALF];
#pragma unroll
    for (int n = 0; n < HALF; ++n) {
        s[n].x = xv[n].x + xv[27 - n].x;
        s[n].y = xv[n].y + xv[27 - n].y;
        u[n].x = xv[n].x - xv[27 - n].x;
        u[n].y = xv[n].y - xv[27 - n].y;
    }

    // ---- weight rows hw0, hw0+1: 2*28 floats = 448 B contiguous = 14 dwordx4.
    // Issued here so L2 latency hides under the forward-DCT FMA block.
    // NOT nontemporal: w is reread once per batch b (16x) -> keep cached.
    const f4v* wp4 = (const f4v*)(w + (size_t)hw0 * C_DIM);
    f4v w0[7], w1[7];
#pragma unroll
    for (int q = 0; q < 7; ++q) w0[q] = wp4[q];      // row hw0
#pragma unroll
    for (int q = 0; q < 7; ++q) w1[q] = wp4[7 + q];  // row hw0+1

    // ---- forward: Xd = D*x via fold. Even k uses s, odd k uses u.
    // 28 independent chains of length 14, per pixel component.
    f2v xd[C_DIM];
#pragma unroll
    for (int k = 0; k < C_DIM; ++k) {
        const float c = TBL.D[k][0];
        xd[k].x = c * ((k & 1) ? u[0].x : s[0].x);
        xd[k].y = c * ((k & 1) ? u[0].y : s[0].y);
    }
#pragma unroll
    for (int n = 1; n < HALF; ++n) {
#pragma unroll
        for (int k = 0; k < C_DIM; ++k) {
            const float c = TBL.D[k][n];
            if (k & 1) {
                xd[k].x = fmaf(c, u[n].x, xd[k].x);
                xd[k].y = fmaf(c, u[n].y, xd[k].y);
            } else {
                xd[k].x = fmaf(c, s[n].x, xd[k].x);
                xd[k].y = fmaf(c, s[n].y, xd[k].y);
            }
        }
    }

    // ---- spectral filter: per-pixel weight row (register "transpose" is free:
    // component r of xd[4q+i] multiplies row-r chunk q component i).
#pragma unroll
    for (int q = 0; q < 7; ++q) {
#pragma unroll
        for (int i = 0; i < 4; ++i) {
            xd[4 * q + i].x *= w0[q][i];
            xd[4 * q + i].y *= w1[q][i];
        }
    }

    // ---- inverse: o = Dinv*xd via fold. e = even-k partial, f = odd-k partial;
    // o[n] = e+f, o[27-n] = e-f. 28 chains of length 14 per component.
    f2v e[HALF], f[HALF];
#pragma unroll
    for (int n = 0; n < HALF; ++n) {
        e[n].x = TBL.Dinv[n][0] * xd[0].x;
        e[n].y = TBL.Dinv[n][0] * xd[0].y;
        f[n].x = TBL.Dinv[n][1] * xd[1].x;
        f[n].y = TBL.Dinv[n][1] * xd[1].y;
    }
#pragma unroll
    for (int j = 1; j < HALF; ++j) {
#pragma unroll
        for (int n = 0; n < HALF; ++n) {
            const float ce = TBL.Dinv[n][2 * j];
            const float cf = TBL.Dinv[n][2 * j + 1];
            e[n].x = fmaf(ce, xd[2 * j].x, e[n].x);
            e[n].y = fmaf(ce, xd[2 * j].y, e[n].y);
            f[n].x = fmaf(cf, xd[2 * j + 1].x, f[n].x);
            f[n].y = fmaf(cf, xd[2 * j + 1].y, f[n].y);
        }
    }

    // ---- stores: 28 NORMAL dwordx2 stores (round-3 experiment: write-back
    // through L2, same path the 6.7 TB/s harness memsets use).
#pragma unroll
    for (int n = 0; n < HALF; ++n) {
        f2v lo, hi;
        lo.x = e[n].x + f[n].x;  lo.y = e[n].y + f[n].y;
        hi.x = e[n].x - f[n].x;  hi.y = e[n].y - f[n].y;
        *(f2v*)(op + (size_t)n * HW) = lo;
        *(f2v*)(op + (size_t)(27 - n) * HW) = hi;
    }
}

extern "C" void kernel_launch(void* const* d_in, const int* in_sizes, int n_in,
                              void* d_out, int out_size, void* d_ws, size_t ws_size,
                              hipStream_t stream) {
    const float* x = (const float*)d_in[0];   // [16,28,256,256]
    const float* w = (const float*)d_in[1];   // [256,256,28]
    float* out = (float*)d_out;               // [16,28,256,256]

    spedct_kernel<<<dim3(GRID), dim3(THREADS), 0, stream>>>(x, w, out);
}